// Round 25
// baseline (125.701 us; speedup 1.0000x reference)
//
#include <hip/hip_runtime.h>
#include <hip/hip_bf16.h>

#define NN 8192
#define CC 256
#define CQK 32
#define JS 4   // pass1 j-splits

using bf16x8 = __attribute__((ext_vector_type(8))) short;
using f16x8  = __attribute__((ext_vector_type(8))) _Float16;
using s16x4  = __attribute__((ext_vector_type(4))) short;
using f32x4  = __attribute__((ext_vector_type(4))) float;
using f32x16 = __attribute__((ext_vector_type(16))) float;

static __device__ __forceinline__ unsigned short f2bf(float x) {
    union { __hip_bfloat16 h; unsigned short u; } cv;
    cv.h = __float2bfloat16(x);
    return cv.u;
}
static __device__ __forceinline__ float bf2f(unsigned short u) {
    union { unsigned u; float f; } cv;
    cv.u = (unsigned)u << 16;
    return cv.f;
}
static __device__ __forceinline__ float fexp2(float x) { return __builtin_amdgcn_exp2f(x); }
// pack two positive f32 -> packed bf16 dword by TRUNCATION (P > 0 always).
static __device__ __forceinline__ int packbf(float lo, float hi) {
    union { float f; unsigned u; } a, b;
    a.f = lo; b.f = hi;
    return (int)((b.u & 0xFFFF0000u) | (a.u >> 16));
}

// ---------------------------------------------------------------------------
// Kernel 1: proj_q. q = (f @ Wqk^T)*sqrt(log2 e) -> single f16
// (r14/r15-validated: absmax == f16 rounding model).
// ---------------------------------------------------------------------------
__global__ __launch_bounds__(256) void proj_q_kernel(
    const float* __restrict__ f, const float* __restrict__ Wqk,
    unsigned short* __restrict__ qf)
{
    __shared__ __align__(16) float fl[8][CC];
    const int t  = threadIdx.x;
    const int r0 = blockIdx.x * 8;
    {
        const float4* src = (const float4*)(f + (size_t)r0 * CC);
        float4* dst = (float4*)&fl[0][0];
        dst[t]       = src[t];
        dst[t + 256] = src[t + 256];
    }
    __syncthreads();
    const int cq = t & 31;
    const int rg = t >> 5;
    const float4* w4 = (const float4*)(Wqk + (size_t)cq * CC);
    float a = 0.f;
    for (int k4 = 0; k4 < 64; ++k4) {
        float4 wq = w4[k4];
        const float4 fv = *(const float4*)&fl[rg][k4 * 4];
        a = fmaf(wq.x, fv.x, a);
        a = fmaf(wq.y, fv.y, a);
        a = fmaf(wq.z, fv.z, a);
        a = fmaf(wq.w, fv.w, a);
    }
    a *= 1.2011224087864498f;              // sqrt(log2 e) -> exp2 domain
    union { _Float16 h; unsigned short u; } cv;
    cv.h = (_Float16)a;                    // RNE
    qf[(size_t)(r0 + rg) * CQK + cq] = cv.u;
}

// ---------------------------------------------------------------------------
// Kernel 2: fused pass1 + proj_v (one launch; proj_v needs only f/Wv so it
// overlaps pass1's denominator sweep).
// ---------------------------------------------------------------------------
__global__ __launch_bounds__(256, 4) void pass1v_kernel(
    const unsigned short* __restrict__ qf,
    const float* __restrict__ f, const float* __restrict__ Wv,
    const float* __restrict__ bv,
    float* __restrict__ ps, unsigned short* __restrict__ vB)
{
    __shared__ float rs[4][32];
    const int t    = threadIdx.x;
    const int lane = t & 63;
    const int w    = t >> 6;
    const int l31  = lane & 31;
    const int h    = lane >> 5;

    if (blockIdx.x < (NN / 32) * JS) {
        // ---- pass1 ----
        const int i0   = (blockIdx.x & 255) * 32;
        const int js   = blockIdx.x >> 8;
        const int JCH  = NN / JS / 4;            // 512 j per wave
        const int jbase = js * (NN / JS) + w * JCH;

        const size_t qir = (size_t)(i0 + l31) * CQK;
        const f16x8 bi0 = *(const f16x8*)(qf + qir + 8 * h);
        const f16x8 bi1 = *(const f16x8*)(qf + qir + 16 + 8 * h);

        float s = 0.f;

#pragma unroll 2
        for (int st = 0; st < JCH; st += 32) {
            const size_t qjr = (size_t)(jbase + st + l31) * CQK;
            const f16x8 aj0 = *(const f16x8*)(qf + qjr + 8 * h);
            const f16x8 aj1 = *(const f16x8*)(qf + qjr + 16 + 8 * h);
            f32x16 ee = {0,0,0,0,0,0,0,0,0,0,0,0,0,0,0,0};
            ee = __builtin_amdgcn_mfma_f32_32x32x16_f16(aj0, bi0, ee, 0, 0, 0);
            ee = __builtin_amdgcn_mfma_f32_32x32x16_f16(aj1, bi1, ee, 0, 0, 0);
            float a_ = 0.f;
#pragma unroll
            for (int r = 0; r < 16; ++r) a_ += fexp2(ee[r]);
            s += a_;
        }
        s += __shfl_xor(s, 32);      // merge the two h-halves (same i-col)

        if (lane < 32) rs[w][l31] = s;
        __syncthreads();
        if (t < 32) {
            float sf = rs[0][t] + rs[1][t] + rs[2][t] + rs[3][t];
            ps[(size_t)js * NN + i0 + t] = sf;
        }
    } else {
        // ---- proj_v ----
        const int nb = (blockIdx.x - (NN / 32) * JS) * 32;
        const int cb = w * 64;

        f32x16 acc[2];
#pragma unroll
        for (int cf = 0; cf < 2; ++cf)
#pragma unroll
            for (int r = 0; r < 16; ++r) acc[cf][r] = 0.f;

        const float* frow = f + (size_t)(nb + l31) * CC;
#pragma unroll
        for (int ks = 0; ks < 16; ++ks) {
            const int k0 = ks * 16 + 8 * h;
            float4 a0 = *(const float4*)(frow + k0);
            float4 a1 = *(const float4*)(frow + k0 + 4);
            bf16x8 af;
            af[0] = (short)f2bf(a0.x); af[1] = (short)f2bf(a0.y);
            af[2] = (short)f2bf(a0.z); af[3] = (short)f2bf(a0.w);
            af[4] = (short)f2bf(a1.x); af[5] = (short)f2bf(a1.y);
            af[6] = (short)f2bf(a1.z); af[7] = (short)f2bf(a1.w);
#pragma unroll
            for (int cf = 0; cf < 2; ++cf) {
                const float* wrow = Wv + (size_t)(cb + 32 * cf + l31) * CC + k0;
                float4 b0 = *(const float4*)(wrow);
                float4 b1 = *(const float4*)(wrow + 4);
                bf16x8 bw;
                bw[0] = (short)f2bf(b0.x); bw[1] = (short)f2bf(b0.y);
                bw[2] = (short)f2bf(b0.z); bw[3] = (short)f2bf(b0.w);
                bw[4] = (short)f2bf(b1.x); bw[5] = (short)f2bf(b1.y);
                bw[6] = (short)f2bf(b1.z); bw[7] = (short)f2bf(b1.w);
                acc[cf] = __builtin_amdgcn_mfma_f32_32x32x16_bf16(af, bw, acc[cf], 0, 0, 0);
            }
        }
#pragma unroll
        for (int cf = 0; cf < 2; ++cf) {
            const int cg = cb + 32 * cf + l31;
            const float bvc = bv[cg];
#pragma unroll
            for (int rg = 0; rg < 4; ++rg) {
                const int ib = (nb >> 3) + rg;
                s16x4 pk;
#pragma unroll
                for (int r = 0; r < 4; ++r)
                    pk[r] = (short)f2bf(acc[cf][4 * rg + r] + bvc);
                *(s16x4*)(vB + ((size_t)ib * CC + cg) * 8 + 4 * h) = pk;
            }
        }
    }
}

// ---------------------------------------------------------------------------
// Kernel 2b: scalev (r22/r24-validated): vBs[i,c] = vB[i,c] / s_i — folds the
// softmax normalization into V so pass2 needs NO bias at all.
// ---------------------------------------------------------------------------
__global__ __launch_bounds__(256) void scalev_kernel(
    const float* __restrict__ ps, const unsigned short* __restrict__ vB,
    unsigned short* __restrict__ vBs)
{
    const int idx = blockIdx.x * 256 + threadIdx.x;   // ib*256 + c
    const int ib  = idx >> 8;
    float rin[8];
#pragma unroll
    for (int ie = 0; ie < 8; ++ie) {
        const int i = ib * 8 + ie;
        float s = ps[i] + ps[NN + i] + ps[2 * NN + i] + ps[3 * NN + i];
        rin[ie] = 1.0f / s;
    }
    const s16x4 v0 = *(const s16x4*)(vB + (size_t)idx * 8);
    const s16x4 v1 = *(const s16x4*)(vB + (size_t)idx * 8 + 4);
    s16x4 o0, o1;
#pragma unroll
    for (int k = 0; k < 4; ++k) {
        o0[k] = (short)f2bf(bf2f((unsigned short)v0[k]) * rin[k]);
        o1[k] = (short)f2bf(bf2f((unsigned short)v1[k]) * rin[4 + k]);
    }
    *(s16x4*)(vBs + (size_t)idx * 8)     = o0;
    *(s16x4*)(vBs + (size_t)idx * 8 + 4) = o1;
}

// ---------------------------------------------------------------------------
// P redistribution (r19-validated): one permlane32_swap yields both words.
// ---------------------------------------------------------------------------
static __device__ __forceinline__ void swap2(int a_, int b_, int& lo, int& hi) {
#if __has_builtin(__builtin_amdgcn_permlane32_swap)
    auto r = __builtin_amdgcn_permlane32_swap(a_, b_, false, false);
    lo = r[0];   // {a.lo, b.lo}
    hi = r[1];   // {a.hi, b.hi}
#else
    const int h_ = (threadIdx.x & 63) >> 5;
    const int pa = __shfl_xor(a_, 32);
    const int pb = __shfl_xor(b_, 32);
    lo = h_ ? pb : a_;
    hi = h_ ? b_ : pa;
#endif
}

// ---------------------------------------------------------------------------
// Kernel 3: LEAN bias-free PV at 4 waves/SIMD.
// Occupancy ledger (m69 buckets: waves/SIMD = 8/4/2 at <=64/<=128/<=256 regs):
// r24's loop = 140 unified -> 2-wave bucket. This loop = r14's lean unroll-1
// single-buffered shape (64 arch VGPR measured there) MINUS all bias state
// (r24) -> ~120 unified -> 4-wave bucket. Grid 1024 (ISPLIT=8, 4 blocks/CU)
// supplies 16 waves/CU; TLP replaces the manual prefetch (which r14 showed is
// needed only at 2 waves). (256,4) is safe here (need ~120 <= 128; r6's spill
// was forcing 152 into 128). isp = bid&7: one isp per XCD, L2-resident slices.
// ---------------------------------------------------------------------------
#define LOADQF(A0, A1, NI)                                                     \
    {                                                                          \
        const size_t qnr = (size_t)((NI) + l31) * CQK;                         \
        A0 = *(const f16x8*)(qf + qnr + 8 * h);                                \
        A1 = *(const f16x8*)(qf + qnr + 16 + 8 * h);                           \
    }

#define LOADVF2(VF, I)                                                         \
    _Pragma("unroll")                                                          \
    for (int s2 = 0; s2 < 2; ++s2)                                             \
        _Pragma("unroll")                                                      \
        for (int cf = 0; cf < 4; ++cf)                                         \
            VF[s2][cf] = *(const bf16x8*)(                                     \
                vBs + ((size_t)(((I) >> 3) + 2 * s2 + h) * CC + cb + 32 * cf + l31) * 8);

#define ECOMPF(EE, A0, A1)                                                     \
    {                                                                          \
        f32x16 z_ = {0,0,0,0,0,0,0,0,0,0,0,0,0,0,0,0};                         \
        z_ = __builtin_amdgcn_mfma_f32_32x32x16_f16(A1, bj1, z_, 0, 0, 0);     \
        EE = __builtin_amdgcn_mfma_f32_32x32x16_f16(A0, bj0, z_, 0, 0, 0);     \
    }

#define FINISH2(EE, VF)                                                        \
    {                                                                          \
        int d0[4], d1[4];                                                      \
        _Pragma("unroll")                                                      \
        for (int rg = 0; rg < 4; ++rg) {                                       \
            d0[rg] = packbf(fexp2(EE[4 * rg + 0]), fexp2(EE[4 * rg + 1]));     \
            d1[rg] = packbf(fexp2(EE[4 * rg + 2]), fexp2(EE[4 * rg + 3]));     \
        }                                                                      \
        _Pragma("unroll")                                                      \
        for (int s2 = 0; s2 < 2; ++s2) {                                       \
            union { int i[4]; bf16x8 v; } pf;                                  \
            swap2(d0[2 * s2], d0[2 * s2 + 1], pf.i[0], pf.i[2]);               \
            swap2(d1[2 * s2], d1[2 * s2 + 1], pf.i[1], pf.i[3]);               \
            _Pragma("unroll")                                                  \
            for (int cf = 0; cf < 4; ++cf)                                     \
                acc[cf] = __builtin_amdgcn_mfma_f32_32x32x16_bf16(             \
                    pf.v, VF[s2][cf], acc[cf], 0, 0, 0);                       \
        }                                                                      \
    }

template<int ISPLIT, bool DIRECT>
__global__ __launch_bounds__(256, 4) void pass2_kernel(
    const unsigned short* __restrict__ qf,
    const unsigned short* __restrict__ vBs,
    const float* __restrict__ f,
    const float* __restrict__ gp,
    void* __restrict__ dstv)
{
    const int t    = threadIdx.x;
    const int lane = t & 63;
    const int w    = t >> 6;
    const int l31  = lane & 31;
    const int h    = lane >> 5;
    const int bid  = blockIdx.x;

    int jblk, isp;
    if (ISPLIT == 8) {
        isp  = bid & 7;                         // one isp per XCD
        jblk = bid >> 3;                        // 0..127
    } else if (ISPLIT == 4) {
        isp  = (bid & 7) >> 1;
        jblk = ((bid >> 3) << 1) | (bid & 1);   // 0..127, bijective
    } else if (ISPLIT == 2) {
        isp  = bid & 1;
        jblk = bid >> 1;
    } else {
        isp  = 0;
        jblk = bid;
    }
    const int jrow = jblk * 64 + 32 * (w & 1);
    const int cb   = 128 * (w >> 1);
    const int IL   = NN / ISPLIT;
    const int ibase = isp * IL;
    const int iend  = ibase + IL;

    const size_t qjr = (size_t)(jrow + l31) * CQK;
    const f16x8 bj0 = *(const f16x8*)(qf + qjr + 8 * h);
    const f16x8 bj1 = *(const f16x8*)(qf + qjr + 16 + 8 * h);

    f32x16 acc[4];
#pragma unroll
    for (int cf = 0; cf < 4; ++cf)
#pragma unroll
        for (int r = 0; r < 16; ++r) acc[cf][r] = 0.f;

#pragma unroll 1
    for (int i0s = ibase; i0s < iend; i0s += 32) {
        f16x8 a0, a1;
        LOADQF(a0, a1, i0s)
        bf16x8 vf[2][4];
        LOADVF2(vf, i0s)
        f32x16 ee;
        ECOMPF(ee, a0, a1)
        FINISH2(ee, vf)
    }

    if (DIRECT) {
        float* dst = (float*)dstv;
        const float g = gp[0];
#pragma unroll
        for (int cf = 0; cf < 4; ++cf) {
            const int c = cb + 32 * cf + l31;
#pragma unroll
            for (int rg = 0; rg < 4; ++rg)
#pragma unroll
                for (int r = 0; r < 4; ++r) {
                    const int j = jrow + 4 * h + r + 8 * rg;
                    dst[(size_t)j * CC + c] =
                        fmaf(g, acc[cf][4 * rg + r], f[(size_t)j * CC + c]);
                }
        }
    } else {
        unsigned short* part = (unsigned short*)dstv + (size_t)isp * NN * CC;
#pragma unroll
        for (int cf = 0; cf < 4; ++cf) {
            const int c = cb + 32 * cf + l31;
#pragma unroll
            for (int rg = 0; rg < 4; ++rg)
#pragma unroll
                for (int r = 0; r < 4; ++r) {
                    const int j = jrow + 4 * h + r + 8 * rg;
                    part[(size_t)j * CC + c] = f2bf(acc[cf][4 * rg + r]);  // RNE
                }
        }
    }
}

// ---------------------------------------------------------------------------
// Kernel 4: out = gamma * sum_splits(bf16 part) + f  (r16/r17-validated)
// ---------------------------------------------------------------------------
template<int SPLIT>
__global__ __launch_bounds__(256) void reduce_kernel(
    const unsigned short* __restrict__ part, const float* __restrict__ f,
    const float* __restrict__ gp, float* __restrict__ out)
{
    size_t idx = (size_t)blockIdx.x * 256 + threadIdx.x;   // 4-elem units
    float s0 = 0.f, s1 = 0.f, s2 = 0.f, s3 = 0.f;
#pragma unroll
    for (int k = 0; k < SPLIT; ++k) {
        const s16x4 v = *(const s16x4*)(part + (size_t)k * NN * CC + idx * 4);
        s0 += bf2f((unsigned short)v[0]);
        s1 += bf2f((unsigned short)v[1]);
        s2 += bf2f((unsigned short)v[2]);
        s3 += bf2f((unsigned short)v[3]);
    }
    const f32x4 fv = ((const f32x4*)f)[idx];
    const float g = gp[0];
    f32x4 o;
    o[0] = fmaf(g, s0, fv[0]);
    o[1] = fmaf(g, s1, fv[1]);
    o[2] = fmaf(g, s2, fv[2]);
    o[3] = fmaf(g, s3, fv[3]);
    ((f32x4*)out)[idx] = o;
}

// ---------------------------------------------------------------------------
extern "C" void kernel_launch(void* const* d_in, const int* in_sizes, int n_in,
                              void* d_out, int out_size, void* d_ws, size_t ws_size,
                              hipStream_t stream) {
    const float* f     = (const float*)d_in[0];
    const float* Wqk   = (const float*)d_in[1];
    const float* Wv    = (const float*)d_in[2];
    const float* bv    = (const float*)d_in[3];
    const float* gamma = (const float*)d_in[4];
    float* out = (float*)d_out;

    char* ws = (char*)d_ws;
    unsigned short* qf  = (unsigned short*)ws;                         // 512 KB
    unsigned short* vB  = (unsigned short*)(ws + (1 << 20));           // 4 MB
    float* ps   = (float*)(ws + (5 << 20));                            // 128 KB
    unsigned short* vBs = (unsigned short*)(ws + (6 << 20));           // 4 MB
    unsigned short* part = (unsigned short*)(ws + (10 << 20));         // ISPLIT*4 MB

    proj_q_kernel<<<dim3(NN / 8), dim3(256), 0, stream>>>(f, Wqk, qf);
    pass1v_kernel<<<dim3((NN / 32) * JS + NN / 32), dim3(256), 0, stream>>>(
        qf, f, Wv, bv, ps, vB);
    scalev_kernel<<<dim3(1024), dim3(256), 0, stream>>>(ps, vB, vBs);

    const size_t PB = (size_t)NN * CC * 2;   // one bf16 partial buffer: 4 MB
    const size_t B0 = (size_t)10 << 20;
    if (ws_size >= B0 + 8 * PB) {
        pass2_kernel<8, false><<<dim3(128 * 8), dim3(256), 0, stream>>>(qf, vBs, f, gamma, part);
        reduce_kernel<8><<<dim3(NN * CC / 1024), dim3(256), 0, stream>>>(part, f, gamma, out);
    } else if (ws_size >= B0 + 4 * PB) {
        pass2_kernel<4, false><<<dim3(128 * 4), dim3(256), 0, stream>>>(qf, vBs, f, gamma, part);
        reduce_kernel<4><<<dim3(NN * CC / 1024), dim3(256), 0, stream>>>(part, f, gamma, out);
    } else if (ws_size >= B0 + 2 * PB) {
        pass2_kernel<2, false><<<dim3(128 * 2), dim3(256), 0, stream>>>(qf, vBs, f, gamma, part);
        reduce_kernel<2><<<dim3(NN * CC / 1024), dim3(256), 0, stream>>>(part, f, gamma, out);
    } else {
        pass2_kernel<1, true><<<dim3(128), dim3(256), 0, stream>>>(qf, vBs, f, gamma, out);
    }
}

// Round 26
// 120.847 us; speedup vs baseline: 1.0402x; 1.0402x over previous
//
#include <hip/hip_runtime.h>
#include <hip/hip_bf16.h>

#define NN 8192
#define CC 256
#define CQK 32
#define JS 4   // pass1 j-splits

using bf16x8 = __attribute__((ext_vector_type(8))) short;
using f16x8  = __attribute__((ext_vector_type(8))) _Float16;
using s16x4  = __attribute__((ext_vector_type(4))) short;
using f32x4  = __attribute__((ext_vector_type(4))) float;
using f32x16 = __attribute__((ext_vector_type(16))) float;

static __device__ __forceinline__ unsigned short f2bf(float x) {
    union { __hip_bfloat16 h; unsigned short u; } cv;
    cv.h = __float2bfloat16(x);
    return cv.u;
}
static __device__ __forceinline__ float bf2f(unsigned short u) {
    union { unsigned u; float f; } cv;
    cv.u = (unsigned)u << 16;
    return cv.f;
}
static __device__ __forceinline__ float fexp2(float x) { return __builtin_amdgcn_exp2f(x); }
// pack two positive f32 -> packed bf16 dword by TRUNCATION (P > 0 always).
static __device__ __forceinline__ int packbf(float lo, float hi) {
    union { float f; unsigned u; } a, b;
    a.f = lo; b.f = hi;
    return (int)((b.u & 0xFFFF0000u) | (a.u >> 16));
}

// ---------------------------------------------------------------------------
// Kernel 1: proj_q. q = (f @ Wqk^T)*sqrt(log2 e) -> single f16
// (r14/r15-validated: absmax == f16 rounding model).
// ---------------------------------------------------------------------------
__global__ __launch_bounds__(256) void proj_q_kernel(
    const float* __restrict__ f, const float* __restrict__ Wqk,
    unsigned short* __restrict__ qf)
{
    __shared__ __align__(16) float fl[8][CC];
    const int t  = threadIdx.x;
    const int r0 = blockIdx.x * 8;
    {
        const float4* src = (const float4*)(f + (size_t)r0 * CC);
        float4* dst = (float4*)&fl[0][0];
        dst[t]       = src[t];
        dst[t + 256] = src[t + 256];
    }
    __syncthreads();
    const int cq = t & 31;
    const int rg = t >> 5;
    const float4* w4 = (const float4*)(Wqk + (size_t)cq * CC);
    float a = 0.f;
    for (int k4 = 0; k4 < 64; ++k4) {
        float4 wq = w4[k4];
        const float4 fv = *(const float4*)&fl[rg][k4 * 4];
        a = fmaf(wq.x, fv.x, a);
        a = fmaf(wq.y, fv.y, a);
        a = fmaf(wq.z, fv.z, a);
        a = fmaf(wq.w, fv.w, a);
    }
    a *= 1.2011224087864498f;              // sqrt(log2 e) -> exp2 domain
    union { _Float16 h; unsigned short u; } cv;
    cv.h = (_Float16)a;                    // RNE
    qf[(size_t)(r0 + rg) * CQK + cq] = cv.u;
}

// ---------------------------------------------------------------------------
// Kernel 2: fused pass1 + proj_v (one launch; proj_v needs only f/Wv so it
// overlaps pass1's denominator sweep).
// ---------------------------------------------------------------------------
__global__ __launch_bounds__(256, 4) void pass1v_kernel(
    const unsigned short* __restrict__ qf,
    const float* __restrict__ f, const float* __restrict__ Wv,
    const float* __restrict__ bv,
    float* __restrict__ ps, unsigned short* __restrict__ vB)
{
    __shared__ float rs[4][32];
    const int t    = threadIdx.x;
    const int lane = t & 63;
    const int w    = t >> 6;
    const int l31  = lane & 31;
    const int h    = lane >> 5;

    if (blockIdx.x < (NN / 32) * JS) {
        // ---- pass1 ----
        const int i0   = (blockIdx.x & 255) * 32;
        const int js   = blockIdx.x >> 8;
        const int JCH  = NN / JS / 4;            // 512 j per wave
        const int jbase = js * (NN / JS) + w * JCH;

        const size_t qir = (size_t)(i0 + l31) * CQK;
        const f16x8 bi0 = *(const f16x8*)(qf + qir + 8 * h);
        const f16x8 bi1 = *(const f16x8*)(qf + qir + 16 + 8 * h);

        float s = 0.f;

#pragma unroll 2
        for (int st = 0; st < JCH; st += 32) {
            const size_t qjr = (size_t)(jbase + st + l31) * CQK;
            const f16x8 aj0 = *(const f16x8*)(qf + qjr + 8 * h);
            const f16x8 aj1 = *(const f16x8*)(qf + qjr + 16 + 8 * h);
            f32x16 ee = {0,0,0,0,0,0,0,0,0,0,0,0,0,0,0,0};
            ee = __builtin_amdgcn_mfma_f32_32x32x16_f16(aj0, bi0, ee, 0, 0, 0);
            ee = __builtin_amdgcn_mfma_f32_32x32x16_f16(aj1, bi1, ee, 0, 0, 0);
            float a_ = 0.f;
#pragma unroll
            for (int r = 0; r < 16; ++r) a_ += fexp2(ee[r]);
            s += a_;
        }
        s += __shfl_xor(s, 32);      // merge the two h-halves (same i-col)

        if (lane < 32) rs[w][l31] = s;
        __syncthreads();
        if (t < 32) {
            float sf = rs[0][t] + rs[1][t] + rs[2][t] + rs[3][t];
            ps[(size_t)js * NN + i0 + t] = sf;
        }
    } else {
        // ---- proj_v ----
        const int nb = (blockIdx.x - (NN / 32) * JS) * 32;
        const int cb = w * 64;

        f32x16 acc[2];
#pragma unroll
        for (int cf = 0; cf < 2; ++cf)
#pragma unroll
            for (int r = 0; r < 16; ++r) acc[cf][r] = 0.f;

        const float* frow = f + (size_t)(nb + l31) * CC;
#pragma unroll
        for (int ks = 0; ks < 16; ++ks) {
            const int k0 = ks * 16 + 8 * h;
            float4 a0 = *(const float4*)(frow + k0);
            float4 a1 = *(const float4*)(frow + k0 + 4);
            bf16x8 af;
            af[0] = (short)f2bf(a0.x); af[1] = (short)f2bf(a0.y);
            af[2] = (short)f2bf(a0.z); af[3] = (short)f2bf(a0.w);
            af[4] = (short)f2bf(a1.x); af[5] = (short)f2bf(a1.y);
            af[6] = (short)f2bf(a1.z); af[7] = (short)f2bf(a1.w);
#pragma unroll
            for (int cf = 0; cf < 2; ++cf) {
                const float* wrow = Wv + (size_t)(cb + 32 * cf + l31) * CC + k0;
                float4 b0 = *(const float4*)(wrow);
                float4 b1 = *(const float4*)(wrow + 4);
                bf16x8 bw;
                bw[0] = (short)f2bf(b0.x); bw[1] = (short)f2bf(b0.y);
                bw[2] = (short)f2bf(b0.z); bw[3] = (short)f2bf(b0.w);
                bw[4] = (short)f2bf(b1.x); bw[5] = (short)f2bf(b1.y);
                bw[6] = (short)f2bf(b1.z); bw[7] = (short)f2bf(b1.w);
                acc[cf] = __builtin_amdgcn_mfma_f32_32x32x16_bf16(af, bw, acc[cf], 0, 0, 0);
            }
        }
#pragma unroll
        for (int cf = 0; cf < 2; ++cf) {
            const int cg = cb + 32 * cf + l31;
            const float bvc = bv[cg];
#pragma unroll
            for (int rg = 0; rg < 4; ++rg) {
                const int ib = (nb >> 3) + rg;
                s16x4 pk;
#pragma unroll
                for (int r = 0; r < 4; ++r)
                    pk[r] = (short)f2bf(acc[cf][4 * rg + r] + bvc);
                *(s16x4*)(vB + ((size_t)ib * CC + cg) * 8 + 4 * h) = pk;
            }
        }
    }
}

// ---------------------------------------------------------------------------
// Kernel 2b: scalev (r22/r24-validated): vBs[i,c] = vB[i,c] / s_i — folds the
// softmax normalization into V so pass2 needs NO bias at all.
// ---------------------------------------------------------------------------
__global__ __launch_bounds__(256) void scalev_kernel(
    const float* __restrict__ ps, const unsigned short* __restrict__ vB,
    unsigned short* __restrict__ vBs)
{
    const int idx = blockIdx.x * 256 + threadIdx.x;   // ib*256 + c
    const int ib  = idx >> 8;
    float rin[8];
#pragma unroll
    for (int ie = 0; ie < 8; ++ie) {
        const int i = ib * 8 + ie;
        float s = ps[i] + ps[NN + i] + ps[2 * NN + i] + ps[3 * NN + i];
        rin[ie] = 1.0f / s;
    }
    const s16x4 v0 = *(const s16x4*)(vB + (size_t)idx * 8);
    const s16x4 v1 = *(const s16x4*)(vB + (size_t)idx * 8 + 4);
    s16x4 o0, o1;
#pragma unroll
    for (int k = 0; k < 4; ++k) {
        o0[k] = (short)f2bf(bf2f((unsigned short)v0[k]) * rin[k]);
        o1[k] = (short)f2bf(bf2f((unsigned short)v1[k]) * rin[4 + k]);
    }
    *(s16x4*)(vBs + (size_t)idx * 8)     = o0;
    *(s16x4*)(vBs + (size_t)idx * 8 + 4) = o1;
}

// ---------------------------------------------------------------------------
// P redistribution (r19-validated): one permlane32_swap yields both words.
// ---------------------------------------------------------------------------
static __device__ __forceinline__ void swap2(int a_, int b_, int& lo, int& hi) {
#if __has_builtin(__builtin_amdgcn_permlane32_swap)
    auto r = __builtin_amdgcn_permlane32_swap(a_, b_, false, false);
    lo = r[0];   // {a.lo, b.lo}
    hi = r[1];   // {a.hi, b.hi}
#else
    const int h_ = (threadIdx.x & 63) >> 5;
    const int pa = __shfl_xor(a_, 32);
    const int pb = __shfl_xor(b_, 32);
    lo = h_ ? pb : a_;
    hi = h_ ? b_ : pa;
#endif
}

// ---------------------------------------------------------------------------
// Kernel 3: barrier-free PV, BIAS-FREE (r24-validated, 61.2 us): p = exp2(e)
// unnormalized, V pre-scaled by 1/s_i. f16 E (2-MFMA chain, zero C-init),
// prefetched double-buffered macro-step, permlane swap, bf16 partials,
// anti-convoy stagger. Per-SIMD issue-bound (r25: 4 waves/SIMD did not beat
// this prefetched 2-wave config — wall == sum of issued work).
// grid 128*ISPLIT x 256 thr (4 waves). Block: 64j x 256c. Wave: 32j x 128c.
// __launch_bounds__(256,2): no register cap (r6 lesson).
// ---------------------------------------------------------------------------
#define LOADQF(A0, A1, NI)                                                     \
    {                                                                          \
        const size_t qnr = (size_t)((NI) + l31) * CQK;                         \
        A0 = *(const f16x8*)(qf + qnr + 8 * h);                                \
        A1 = *(const f16x8*)(qf + qnr + 16 + 8 * h);                           \
    }

#define LOADVF2(VF, I)                                                         \
    _Pragma("unroll")                                                          \
    for (int s2 = 0; s2 < 2; ++s2)                                             \
        _Pragma("unroll")                                                      \
        for (int cf = 0; cf < 4; ++cf)                                         \
            VF[s2][cf] = *(const bf16x8*)(                                     \
                vBs + ((size_t)(((I) >> 3) + 2 * s2 + h) * CC + cb + 32 * cf + l31) * 8);

#define ECOMPF(EE, A0, A1)                                                     \
    {                                                                          \
        f32x16 z_ = {0,0,0,0,0,0,0,0,0,0,0,0,0,0,0,0};                         \
        z_ = __builtin_amdgcn_mfma_f32_32x32x16_f16(A1, bj1, z_, 0, 0, 0);     \
        EE = __builtin_amdgcn_mfma_f32_32x32x16_f16(A0, bj0, z_, 0, 0, 0);     \
    }

#define FINISH2(EE, VF)                                                        \
    {                                                                          \
        int d0[4], d1[4];                                                      \
        _Pragma("unroll")                                                      \
        for (int rg = 0; rg < 4; ++rg) {                                       \
            d0[rg] = packbf(fexp2(EE[4 * rg + 0]), fexp2(EE[4 * rg + 1]));     \
            d1[rg] = packbf(fexp2(EE[4 * rg + 2]), fexp2(EE[4 * rg + 3]));     \
        }                                                                      \
        _Pragma("unroll")                                                      \
        for (int s2 = 0; s2 < 2; ++s2) {                                       \
            union { int i[4]; bf16x8 v; } pf;                                  \
            swap2(d0[2 * s2], d0[2 * s2 + 1], pf.i[0], pf.i[2]);               \
            swap2(d1[2 * s2], d1[2 * s2 + 1], pf.i[1], pf.i[3]);               \
            _Pragma("unroll")                                                  \
            for (int cf = 0; cf < 4; ++cf)                                     \
                acc[cf] = __builtin_amdgcn_mfma_f32_32x32x16_bf16(             \
                    pf.v, VF[s2][cf], acc[cf], 0, 0, 0);                       \
        }                                                                      \
    }

template<int ISPLIT, bool DIRECT>
__global__ __launch_bounds__(256, 2) void pass2_kernel(
    const unsigned short* __restrict__ qf,
    const unsigned short* __restrict__ vBs,
    const float* __restrict__ f,
    const float* __restrict__ gp,
    void* __restrict__ dstv)
{
    const int t    = threadIdx.x;
    const int lane = t & 63;
    const int w    = t >> 6;
    const int l31  = lane & 31;
    const int h    = lane >> 5;
    const int bid  = blockIdx.x;

    int jblk, isp;
    if (ISPLIT == 4) {
        // XCD-aware: each XCD pair owns one isp -> its vBs/q slices stay in L2
        isp  = (bid & 7) >> 1;
        jblk = ((bid >> 3) << 1) | (bid & 1);   // 0..127, bijective
    } else if (ISPLIT == 2) {
        isp  = bid & 1;
        jblk = bid >> 1;
    } else {
        isp  = 0;
        jblk = bid;
    }
    const int jrow = jblk * 64 + 32 * (w & 1);
    const int cb   = 128 * (w >> 1);
    const int IL   = NN / ISPLIT;            // power of 2
    const int ibase = isp * IL;
    const int off  = ((bid ^ (bid >> 8)) & 1) * 32;   // anti-convoy phase

    const size_t qjr = (size_t)(jrow + l31) * CQK;
    const f16x8 bj0 = *(const f16x8*)(qf + qjr + 8 * h);
    const f16x8 bj1 = *(const f16x8*)(qf + qjr + 16 + 8 * h);

    f32x16 acc[4];
#pragma unroll
    for (int cf = 0; cf < 4; ++cf)
#pragma unroll
        for (int r = 0; r < 16; ++r) acc[cf][r] = 0.f;

    f32x16 eeA, eeB;
    f16x8  qa0, qa1, qb0, qb1;
    bf16x8 vfA[2][4], vfB[2][4];

    // circular chunk index helper: ibase + ((64k + off [+32...]) mod IL)
    const int m = IL - 1;
    const int iA0 = ibase + (off & m);
    const int iB0 = ibase + ((off + 32) & m);

    // prologue: E(chunk0) ready in eeA; qb staged for chunk1; vfA chunk0
    LOADQF(qa0, qa1, iA0)
    LOADVF2(vfA, iA0)
    ECOMPF(eeA, qa0, qa1)
    LOADQF(qb0, qb1, iB0)

    for (int k = 0; k < IL; k += 64) {
        const int iB = ibase + ((k + 32 + off) & m);
        const int n1 = ibase + ((k + 64 + off) & m);   // wraps on last iter:
        const int n2 = ibase + ((k + 96 + off) & m);   // prefetch discarded
        // stage A: E(iB) + vf(iB) in flight over FINISH(iA)
        LOADVF2(vfB, iB)
        ECOMPF(eeB, qb0, qb1)
        LOADQF(qa0, qa1, n1)
        FINISH2(eeA, vfA)
        // stage B: E(n1) + vf(n1) in flight over FINISH(iB)
        LOADVF2(vfA, n1)
        ECOMPF(eeA, qa0, qa1)
        LOADQF(qb0, qb1, n2)
        FINISH2(eeB, vfB)
    }

    if (DIRECT) {
        float* dst = (float*)dstv;
        const float g = gp[0];
#pragma unroll
        for (int cf = 0; cf < 4; ++cf) {
            const int c = cb + 32 * cf + l31;
#pragma unroll
            for (int rg = 0; rg < 4; ++rg)
#pragma unroll
                for (int r = 0; r < 4; ++r) {
                    const int j = jrow + 4 * h + r + 8 * rg;
                    dst[(size_t)j * CC + c] =
                        fmaf(g, acc[cf][4 * rg + r], f[(size_t)j * CC + c]);
                }
        }
    } else {
        unsigned short* part = (unsigned short*)dstv + (size_t)isp * NN * CC;
#pragma unroll
        for (int cf = 0; cf < 4; ++cf) {
            const int c = cb + 32 * cf + l31;
#pragma unroll
            for (int rg = 0; rg < 4; ++rg)
#pragma unroll
                for (int r = 0; r < 4; ++r) {
                    const int j = jrow + 4 * h + r + 8 * rg;
                    part[(size_t)j * CC + c] = f2bf(acc[cf][4 * rg + r]);  // RNE
                }
        }
    }
}

// ---------------------------------------------------------------------------
// Kernel 4: out = gamma * sum_splits(bf16 part) + f  (r16/r17-validated)
// ---------------------------------------------------------------------------
template<int SPLIT>
__global__ __launch_bounds__(256) void reduce_kernel(
    const unsigned short* __restrict__ part, const float* __restrict__ f,
    const float* __restrict__ gp, float* __restrict__ out)
{
    size_t idx = (size_t)blockIdx.x * 256 + threadIdx.x;   // 4-elem units
    float s0 = 0.f, s1 = 0.f, s2 = 0.f, s3 = 0.f;
#pragma unroll
    for (int k = 0; k < SPLIT; ++k) {
        const s16x4 v = *(const s16x4*)(part + (size_t)k * NN * CC + idx * 4);
        s0 += bf2f((unsigned short)v[0]);
        s1 += bf2f((unsigned short)v[1]);
        s2 += bf2f((unsigned short)v[2]);
        s3 += bf2f((unsigned short)v[3]);
    }
    const f32x4 fv = ((const f32x4*)f)[idx];
    const float g = gp[0];
    f32x4 o;
    o[0] = fmaf(g, s0, fv[0]);
    o[1] = fmaf(g, s1, fv[1]);
    o[2] = fmaf(g, s2, fv[2]);
    o[3] = fmaf(g, s3, fv[3]);
    ((f32x4*)out)[idx] = o;
}

// ---------------------------------------------------------------------------
extern "C" void kernel_launch(void* const* d_in, const int* in_sizes, int n_in,
                              void* d_out, int out_size, void* d_ws, size_t ws_size,
                              hipStream_t stream) {
    const float* f     = (const float*)d_in[0];
    const float* Wqk   = (const float*)d_in[1];
    const float* Wv    = (const float*)d_in[2];
    const float* bv    = (const float*)d_in[3];
    const float* gamma = (const float*)d_in[4];
    float* out = (float*)d_out;

    char* ws = (char*)d_ws;
    unsigned short* qf  = (unsigned short*)ws;                         // 512 KB
    unsigned short* vB  = (unsigned short*)(ws + (1 << 20));           // 4 MB
    float* ps   = (float*)(ws + (5 << 20));                            // 128 KB
    unsigned short* vBs = (unsigned short*)(ws + (6 << 20));           // 4 MB
    unsigned short* part = (unsigned short*)(ws + (10 << 20));         // ISPLIT*4 MB

    proj_q_kernel<<<dim3(NN / 8), dim3(256), 0, stream>>>(f, Wqk, qf);
    pass1v_kernel<<<dim3((NN / 32) * JS + NN / 32), dim3(256), 0, stream>>>(
        qf, f, Wv, bv, ps, vB);
    scalev_kernel<<<dim3(1024), dim3(256), 0, stream>>>(ps, vB, vBs);

    const size_t PB = (size_t)NN * CC * 2;   // one bf16 partial buffer: 4 MB
    const size_t B0 = (size_t)10 << 20;
    if (ws_size >= B0 + 4 * PB) {
        pass2_kernel<4, false><<<dim3(128 * 4), dim3(256), 0, stream>>>(qf, vBs, f, gamma, part);
        reduce_kernel<4><<<dim3(NN * CC / 1024), dim3(256), 0, stream>>>(part, f, gamma, out);
    } else if (ws_size >= B0 + 2 * PB) {
        pass2_kernel<2, false><<<dim3(128 * 2), dim3(256), 0, stream>>>(qf, vBs, f, gamma, part);
        reduce_kernel<2><<<dim3(NN * CC / 1024), dim3(256), 0, stream>>>(part, f, gamma, out);
    } else {
        pass2_kernel<1, true><<<dim3(128), dim3(256), 0, stream>>>(qf, vBs, f, gamma, out);
    }
}